// Round 12
// baseline (342.563 us; speedup 1.0000x reference)
//
#include <hip/hip_runtime.h>

// Problem constants (B, L_IN, D) = (4, 4096, 1024)
#define BB 4
#define LL 4096
#define DD 1024
#define SS 64   // number of chunks in the scan
#define TT 64   // chunk length (SS*TT == LL)
#define NCH 16  // chains: (DD/256) * BB

typedef __attribute__((ext_vector_type(4))) float  floatx4;
typedef __attribute__((ext_vector_type(8))) short  shortx8;
typedef __attribute__((ext_vector_type(8))) unsigned short ushortx8;

static __device__ __forceinline__ unsigned short f2bf(float f) {
    unsigned int u = __float_as_uint(f);
    u += 0x7fffu + ((u >> 16) & 1u);           // round-to-nearest-even
    return (unsigned short)(u >> 16);
}
static __device__ __forceinline__ float bf2f(unsigned short h) {
    return __uint_as_float(((unsigned int)h) << 16);
}

// ---------------- small cast: Wi + Wo-interleaved + flag zeroing -------------
// The big input cast is GONE: GEMM1 now converts f32->bf16 during A-staging.
// Wo is cast WITH K-column interleave: WoP[n][2d] = Wo[n][d] (re),
// WoP[n][2d+1] = Wo[n][DD+d] (im) — matches scan's interleaved xr layout.
#define NWI4 (2 * DD * DD / 4)           // 524288
#define NWO8 (DD * DD / 4)               // 262144 (8 outputs/thread)
__global__ void cast_wb_kernel(const float4* __restrict__ s_wi, ushort4* __restrict__ d_wib,
                               const float* __restrict__ s_wo, unsigned short* __restrict__ d_wob,
                               int* __restrict__ flags) {
    int i = blockIdx.x * blockDim.x + threadIdx.x;
    if (i < NCH * SS)
        __hip_atomic_store(&flags[i], 0, __ATOMIC_RELAXED, __HIP_MEMORY_SCOPE_AGENT);
    if (i < NWI4) {
        float4 v = s_wi[i];
        ushort4 o;
        o.x = f2bf(v.x); o.y = f2bf(v.y); o.z = f2bf(v.z); o.w = f2bf(v.w);
        d_wib[i] = o;
    } else {
        int j = i - NWI4;                      // j < NWO8
        int n  = j >> 8;                       // row (DD/4 = 256 quads per row)
        int d0 = (j & 255) * 4;
        const float* rowp = s_wo + (size_t)n * (2 * DD);
        float4 re = *(const float4*)(rowp + d0);
        float4 im = *(const float4*)(rowp + DD + d0);
        ushortx8 o;
        o[0] = f2bf(re.x); o[1] = f2bf(im.x);
        o[2] = f2bf(re.y); o[3] = f2bf(im.y);
        o[4] = f2bf(re.z); o[5] = f2bf(im.z);
        o[6] = f2bf(re.w); o[7] = f2bf(im.w);
        *(ushortx8*)(d_wob + (size_t)n * (2 * DD) + 2 * d0) = o;
    }
}

// ---------------- bf16 GEMM: C[M,N] = A[M,K] * B[N,K]^T + bias ----------------
// Proven r2 4-phase read-ahead schedule. AF32=1: A is f32 in HBM; staged via
// {issue 4 float4 (ph1/ph3) -> cvt + 2 ds_write_b128 one phase later
// (ph2/ph4)} — T14 split; the cvt's implicit vmcnt wait replaces part of the
// counted-wait arithmetic (A-loads issued BEFORE B-GLLs in their phase, so
// in-order retirement never prematurely drains younger B-prefetches).
// AF32 ph4 counted wait = vmcnt(6): end-of-ph3 queue (oldest->youngest) =
// B0(t1) GLLx2, A1 f32x4, B1(t2) GLLx2 = 8; keep 6 -> B0(t+1) landed before
// the barrier, enabling end-of-ph4 LOAD_B of next tile. (If the compiler
// reorders A-loads after B-GLLs, ph2's cvt-wait retires B0(t1) even earlier —
// safe either way.) ds_write WAR safety: identical to STAGE_A placement
// (overwrite 2 barriers after the region's last ds_read, lgkm-drained).
template<int K, int NT, int EPI, int AF32>
__global__ __launch_bounds__(512, 2)
void gemm256(const void* __restrict__ Ap,
             const unsigned short* __restrict__ B,
             const float* __restrict__ bias,
             void* __restrict__ Cp) {
    constexpr int N   = NT * 256;
    constexpr int NKT = K / 64;            // 16 or 32 here
    __shared__ __align__(16) short As[2][256 * 64];   // 64 KB
    __shared__ __align__(16) short Bs[2][256 * 64];   // 64 KB

    const unsigned short* A  = (const unsigned short*)Ap;
    const float*          Af = (const float*)Ap;

    const int tid = threadIdx.x;
    const int blk = blockIdx.x;
    const int xcd = blk & 7;
    const int i2  = blk >> 3;
    const int tileM = ((i2 / NT) * 8 + xcd) * 256;
    const int tileN = (i2 % NT) * 256;

    const int lane   = tid & 63;
    const int wave   = tid >> 6;
    const int wave_m = wave >> 2;          // 0..1
    const int wave_n = wave & 3;           // 0..3
    const int r16    = lane & 15;
    const int quad   = lane >> 4;
    const int slotx  = r16 & 7;
    const int wmRow  = wave_m * 64 + r16;
    const int wnRow  = wave_n * 32 + r16;

    const int srow = tid >> 3;                         // 0..63
    const int scol = ((tid & 7) ^ (srow & 7)) * 8;     // pre-swizzled k offset (elems)
    const int ldsChunkBase = (tid & ~63) * 8;          // shorts (GLL: +lane*16B)
    const int ldsWr = tid * 8;                         // shorts (explicit ds_write addr)
    const size_t aOff = (size_t)(tileM + srow) * K + scol;
    const size_t bOff = (size_t)(tileN + srow) * K + scol;

    floatx4 acc[8][4] = {};
    shortx8 af[4][2], bf0v[2][2], bf1v[2][2];
    float4 a0_, a1_, a2_, a3_;             // AF32 staging regs

#define GLL(SRC, DST) __builtin_amdgcn_global_load_lds( \
        (const __attribute__((address_space(1))) void*)(SRC), \
        (__attribute__((address_space(3))) void*)(DST), 16, 0, 0)
#define STAGE_A(BUF, H, KT) do { \
    GLL(A + aOff + (size_t)((H) * 128) * K + (KT) * 64,      &As[BUF][(H) * 8192 + ldsChunkBase]); \
    GLL(A + aOff + (size_t)((H) * 128 + 64) * K + (KT) * 64, &As[BUF][(H) * 8192 + 4096 + ldsChunkBase]); \
} while (0)
#define STAGE_B(BUF, H, KT) do { \
    GLL(B + bOff + (size_t)((H) * 128) * K + (KT) * 64,      &Bs[BUF][(H) * 8192 + ldsChunkBase]); \
    GLL(B + bOff + (size_t)((H) * 128 + 64) * K + (KT) * 64, &Bs[BUF][(H) * 8192 + 4096 + ldsChunkBase]); \
} while (0)
#define AISSUE(H, KT) do { \
    const float* ap_ = Af + aOff + (size_t)((H) * 128) * K + (KT) * 64; \
    a0_ = *(const float4*)ap_;  a1_ = *(const float4*)(ap_ + 4); \
    const float* ap2_ = ap_ + (size_t)64 * K; \
    a2_ = *(const float4*)ap2_; a3_ = *(const float4*)(ap2_ + 4); \
} while (0)
#define AWRITE(BUF, H) do { \
    shortx8 p0_, p1_; \
    p0_[0]=(short)f2bf(a0_.x); p0_[1]=(short)f2bf(a0_.y); p0_[2]=(short)f2bf(a0_.z); p0_[3]=(short)f2bf(a0_.w); \
    p0_[4]=(short)f2bf(a1_.x); p0_[5]=(short)f2bf(a1_.y); p0_[6]=(short)f2bf(a1_.z); p0_[7]=(short)f2bf(a1_.w); \
    p1_[0]=(short)f2bf(a2_.x); p1_[1]=(short)f2bf(a2_.y); p1_[2]=(short)f2bf(a2_.z); p1_[3]=(short)f2bf(a2_.w); \
    p1_[4]=(short)f2bf(a3_.x); p1_[5]=(short)f2bf(a3_.y); p1_[6]=(short)f2bf(a3_.z); p1_[7]=(short)f2bf(a3_.w); \
    *(shortx8*)&As[BUF][(H) * 8192 + ldsWr]        = p0_; \
    *(shortx8*)&As[BUF][(H) * 8192 + 4096 + ldsWr] = p1_; \
} while (0)
#define LOAD_A(BUF, MH) do { \
    _Pragma("unroll") for (int il = 0; il < 4; ++il) \
    _Pragma("unroll") for (int kk = 0; kk < 2; ++kk) \
        af[il][kk] = *(const shortx8*)&As[BUF][((MH) * 128 + wmRow + il * 16) * 64 + ((kk * 4 + quad) ^ slotx) * 8]; \
} while (0)
#define LOAD_B(BUF, NH, DST) do { \
    _Pragma("unroll") for (int jl = 0; jl < 2; ++jl) \
    _Pragma("unroll") for (int kk = 0; kk < 2; ++kk) \
        DST[jl][kk] = *(const shortx8*)&Bs[BUF][((NH) * 128 + wnRow + jl * 16) * 64 + ((kk * 4 + quad) ^ slotx) * 8]; \
} while (0)
#define MFMAQ(MH, NH, BF) do { \
    __builtin_amdgcn_s_setprio(1); \
    _Pragma("unroll") for (int kk = 0; kk < 2; ++kk) \
    _Pragma("unroll") for (int il = 0; il < 4; ++il) \
    _Pragma("unroll") for (int jl = 0; jl < 2; ++jl) \
        acc[(MH) * 4 + il][(NH) * 2 + jl] = __builtin_amdgcn_mfma_f32_16x16x32_bf16( \
            af[il][kk], BF[jl][kk], acc[(MH) * 4 + il][(NH) * 2 + jl], 0, 0, 0); \
    __builtin_amdgcn_s_setprio(0); \
} while (0)
#define BAR()  __builtin_amdgcn_s_barrier()
#define LGKM0() asm volatile("s_waitcnt lgkmcnt(0)" ::: "memory")

    if constexpr (AF32) {
        // prologue: convert+stage A(0),A(1); GLL-stage B0(0),B1(0),B1(1)
        AISSUE(0, 0); AWRITE(0, 0);
        AISSUE(1, 0); AWRITE(0, 1);
        STAGE_B(0, 0, 0);
        STAGE_B(0, 1, 0);
        AISSUE(0, 1); AWRITE(1, 0);        // cvt-wait also retires B0(0),B1(0)
        AISSUE(1, 1); AWRITE(1, 1);
        STAGE_B(1, 1, 1);
        asm volatile("s_waitcnt vmcnt(2)" ::: "memory");  // B1(1) stays in flight
        LGKM0();                            // own ds_writes drained
        BAR();
    } else {
        // prologue: tile0 (A0,B0,B1,A1) + A0(1),B1(1),A1(1) = 14 GLLs
        STAGE_A(0, 0, 0);
        STAGE_B(0, 0, 0);
        STAGE_B(0, 1, 0);
        STAGE_A(0, 1, 0);
        STAGE_A(1, 0, 1);
        STAGE_B(1, 1, 1);
        STAGE_A(1, 1, 1);
        asm volatile("s_waitcnt vmcnt(6)" ::: "memory");
        BAR();
    }
    // pre-issue ph1(t=0) operands
    LOAD_A(0, 0);
    LOAD_B(0, 0, bf0v);

#pragma unroll 2
    for (int t = 0; t < NKT; ++t) {
        const int cb = t & 1;
        const int t1 = (t + 1 < NKT) ? t + 1 : NKT - 1;   // clamped tail: keeps
        const int t2 = (t + 2 < NKT) ? t + 2 : NKT - 1;   // wait counts uniform
        // ---- phase 1: Q(0,0) ----
        BAR();
        LGKM0();
        if constexpr (AF32) AISSUE(0, t2);  // issue BEFORE B-GLLs (retire order)
        STAGE_B(cb ^ 1, 0, t1);
        MFMAQ(0, 0, bf0v);
        LOAD_B(cb, 1, bf1v);           // read-ahead for ph2
        // ---- phase 2: Q(0,1) ----
        BAR();
        LGKM0();
        if constexpr (AF32) AWRITE(cb, 0); else STAGE_A(cb, 0, t2);
        MFMAQ(0, 1, bf1v);
        LOAD_A(cb, 1);                 // read-ahead for ph3
        // ---- phase 3: Q(1,0) ----
        BAR();
        LGKM0();
        if constexpr (AF32) AISSUE(1, t2);
        STAGE_B(cb, 1, t2);
        MFMAQ(1, 0, bf0v);
        // ---- phase 4: Q(1,1) ----
        if constexpr (AF32) { asm volatile("s_waitcnt vmcnt(6)" ::: "memory"); }
        else                { asm volatile("s_waitcnt vmcnt(4)" ::: "memory"); }
        BAR();
        if constexpr (AF32) AWRITE(cb, 1); else STAGE_A(cb, 1, t2);
        MFMAQ(1, 1, bf1v);
        LOAD_A(cb ^ 1, 0);             // read-ahead for next tile's ph1
        LOAD_B(cb ^ 1, 0, bf0v);       // (tile t+1 fully landed pre-barrier)
    }
    asm volatile("s_waitcnt vmcnt(0) lgkmcnt(0)" ::: "memory");  // drain tail

    // epilogue
#pragma unroll
    for (int i = 0; i < 8; ++i) {
        const int row0 = tileM + (i >> 2) * 128 + wave_m * 64 + (i & 3) * 16 + quad * 4;
#pragma unroll
        for (int j = 0; j < 4; ++j) {
            const int col = tileN + (j >> 1) * 128 + wave_n * 32 + (j & 1) * 16 + r16;
            const float bv = bias[col];
#pragma unroll
            for (int r = 0; r < 4; ++r) {
                float v = acc[i][j][r] + bv;
                if (EPI == 0) {
                    ((unsigned short*)Cp)[(size_t)(row0 + r) * N + col] = f2bf(v);
                } else {
                    ((float*)Cp)[(size_t)(row0 + r) * N + col] = fmaxf(v, 0.0f);
                }
            }
        }
    }
#undef GLL
#undef STAGE_A
#undef STAGE_B
#undef AISSUE
#undef AWRITE
#undef LOAD_A
#undef LOAD_B
#undef MFMAQ
#undef BAR
#undef LGKM0
}

// ---------------- ONE-PASS scan (r11, proven): flag-wait, LDS-hybrid --------
// Relaxed write-through protocol (no acquire/release -> no buffer_inv storm).
// Co-residency by construction (32 KB LDS, VGPR<=128, 256 thr -> 4 blocks/CU,
// 1024 blocks all resident) -> flag-wait deadlock-free under any dispatch order.
__global__ __launch_bounds__(256, 4)
void scan_onepass(const unsigned short* __restrict__ u,
                  const float* __restrict__ plog,
                  unsigned long long* __restrict__ Epub,
                  int* __restrict__ flags,
                  unsigned short* __restrict__ xr) {
    __shared__ unsigned int wl[32][256];               // 32 KB, column-private
    const int tid = threadIdx.x;
    const int d = blockIdx.x * 256 + tid;
    const int c = blockIdx.y, b = blockIdx.z;
    const int chain = b * (DD / 256) + blockIdx.x;     // 0..15

    // ---- load chunk: first 32 steps -> registers, last 32 -> LDS ----
    unsigned int w[32];
    {
        const unsigned short* up = u + (size_t)(b * LL + c * TT) * (2 * DD) + 2 * d;
#pragma unroll
        for (int tl = 0; tl < 32; ++tl) { w[tl] = *(const unsigned int*)up; up += 2 * DD; }
#pragma unroll
        for (int tl = 0; tl < 32; ++tl) { wl[tl][tid] = *(const unsigned int*)up; up += 2 * DD; }
    }
    const float v  = expf(plog[d]);
    const float th = expf(plog[DD + d]);
    const float a  = expf(-v);
    const float lr = a * cosf(th), li = a * sinf(th);

    // ---- phase A: local scan + publish (relaxed write-through) ----
    {
        float zr = 0.f, zi = 0.f;
#pragma unroll
        for (int tl = 0; tl < 32; ++tl) {
            float xv = bf2f((unsigned short)(w[tl] & 0xffffu));
            float yv = bf2f((unsigned short)(w[tl] >> 16));
            float t = lr * zr - li * zi + xv;
            zi = lr * zi + li * zr + yv;
            zr = t;
        }
#pragma unroll 8
        for (int tl = 0; tl < 32; ++tl) {
            unsigned int q = wl[tl][tid];
            float xv = bf2f((unsigned short)(q & 0xffffu));
            float yv = bf2f((unsigned short)(q >> 16));
            float t = lr * zr - li * zi + xv;
            zi = lr * zi + li * zr + yv;
            zr = t;
        }
        unsigned long long q = (unsigned long long)__float_as_uint(zr) |
                               ((unsigned long long)__float_as_uint(zi) << 32);
        __hip_atomic_store(&Epub[(size_t)c * (BB * DD) + b * DD + d], q,
                           __ATOMIC_RELAXED, __HIP_MEMORY_SCOPE_AGENT);
    }
    asm volatile("s_waitcnt vmcnt(0)" ::: "memory");   // payload ack'd at IC
    __syncthreads();                                    // all waves published
    if (tid == 0)
        __hip_atomic_store(&flags[chain * SS + c], 1,
                           __ATOMIC_RELAXED, __HIP_MEMORY_SCOPE_AGENT);

    // ---- phase B: wait for predecessors (relaxed polls), combine carry ----
    float yr = 0.f, yi = 0.f;
    if (c > 0) {
        const float aT = expf(-(float)TT * v);
        const float Lr = aT * cosf((float)TT * th), Li = aT * sinf((float)TT * th);
        const int fbase = chain * SS;
        if (tid == 0) {                                // one spinner per block
            for (int j0 = 0; j0 < c; j0 += 8) {
                for (;;) {
                    int got = 0;
#pragma unroll
                    for (int k = 0; k < 8; ++k) {
                        got += (j0 + k >= c) ? 1 :
                            (__hip_atomic_load(&flags[fbase + j0 + k],
                                 __ATOMIC_RELAXED, __HIP_MEMORY_SCOPE_AGENT) != 0);
                    }
                    if (got == 8) break;
                    __builtin_amdgcn_s_sleep(8);
                }
            }
        }
        __syncthreads();                               // spinner releases block
        const size_t pbase = (size_t)b * DD + d;
#define PLD(JJ) __hip_atomic_load(&Epub[(size_t)(JJ) * (BB * DD) + pbase], \
                                  __ATOMIC_RELAXED, __HIP_MEMORY_SCOPE_AGENT)
#define COMB(Q) do { \
        float er = __uint_as_float((unsigned int)(Q)); \
        float ei = __uint_as_float((unsigned int)((Q) >> 32)); \
        float t = Lr * yr - Li * yi + er; \
        yi = Lr * yi + Li * yr + ei; \
        yr = t; } while (0)
        int j = 0;
        for (; j + 4 <= c; j += 4) {
            unsigned long long q0 = PLD(j + 0), q1 = PLD(j + 1);
            unsigned long long q2 = PLD(j + 2), q3 = PLD(j + 3);
            COMB(q0); COMB(q1); COMB(q2); COMB(q3);
        }
        for (; j < c; ++j) { unsigned long long q = PLD(j); COMB(q); }
#undef PLD
#undef COMB
    }

    // ---- phase C: rescan (regs then LDS) with carry, store packed (re,im) ----
    {
        const float g = expf(plog[2 * DD + d]);
        unsigned short* xp = xr + (size_t)(b * LL + c * TT) * (2 * DD) + 2 * d;
#pragma unroll
        for (int tl = 0; tl < 32; ++tl) {
            float xv = bf2f((unsigned short)(w[tl] & 0xffffu));
            float yv = bf2f((unsigned short)(w[tl] >> 16));
            float t = lr * yr - li * yi + xv;
            yi = lr * yi + li * yr + yv;
            yr = t;
            *(unsigned int*)xp = (unsigned int)f2bf(g * yr) |
                                 ((unsigned int)f2bf(g * yi) << 16);
            xp += 2 * DD;
        }
#pragma unroll 8
        for (int tl = 0; tl < 32; ++tl) {
            unsigned int q = wl[tl][tid];
            float xv = bf2f((unsigned short)(q & 0xffffu));
            float yv = bf2f((unsigned short)(q >> 16));
            float t = lr * yr - li * yi + xv;
            yi = lr * yi + li * yr + yv;
            yr = t;
            *(unsigned int*)xp = (unsigned int)f2bf(g * yr) |
                                 ((unsigned int)f2bf(g * yi) << 16);
            xp += 2 * DD;
        }
    }
}

extern "C" void kernel_launch(void* const* d_in, const int* in_sizes, int n_in,
                              void* d_out, int out_size, void* d_ws, size_t ws_size,
                              hipStream_t stream) {
    const float* inputs = (const float*)d_in[0];   // B*L*D = 16777216
    const float* Wi     = (const float*)d_in[1];   // 2D*D  = 2097152
    const float* bi     = (const float*)d_in[2];   // 2D
    const float* Wo     = (const float*)d_in[3];   // D*2D  = 2097152
    const float* bo     = (const float*)d_in[4];   // D
    const float* plog   = (const float*)d_in[5];   // 3*D
    float* out = (float*)d_out;

    const size_t M = (size_t)BB * LL;              // 16384
    unsigned short* u_bf  = (unsigned short*)d_ws;             // M*2D bf16  (64 MB)
    unsigned short* xr_bf = u_bf  + M * 2 * DD;                // M*2D bf16  (64 MB)
    unsigned short* spare = xr_bf + M * 2 * DD;                // former in_bf (unused now)
    unsigned short* Wi_bf = spare + M * DD;                    // 2D*D bf16  (4 MB)
    unsigned short* Wo_bf = Wi_bf + (size_t)2 * DD * DD;       // D*2D bf16  (4 MB)
    // Epub (SS*B*D x8B = 2 MB) lives in the now-unused former in_bf region.
    unsigned long long* Epub = (unsigned long long*)spare;
    // flags (NCH*SS ints = 4 KB) after Wo_bf.
    int* flags = (int*)(Wo_bf + (size_t)2 * DD * DD);

    // small cast: Wi + Wo-interleaved + flag zeroing (17 MB traffic)
    cast_wb_kernel<<<(NWI4 + NWO8) / 256, 256, 0, stream>>>(
        (const float4*)Wi, (ushort4*)Wi_bf, Wo, Wo_bf, flags);

    // GEMM1: u[M, 2D] = f32 inputs @ Wi^T + bi (in-kernel A cast), bf16 out
    gemm256<DD, 8, 0, 1><<<(M / 256) * 8, 512, 0, stream>>>(
        (const void*)inputs, Wi_bf, bi, (void*)u_bf);

    // one-pass scan (u read ONCE; relaxed write-through flag protocol)
    scan_onepass<<<dim3(DD / 256, SS, BB), 256, 0, stream>>>(
        u_bf, plog, Epub, flags, xr_bf);

    // GEMM2: out[M, D] = relu(xr[M, 2D] @ WoP^T + bo)  (f32 out)
    gemm256<2 * DD, 4, 1, 0><<<(M / 256) * 4, 512, 0, stream>>>(
        (const void*)xr_bf, Wo_bf, bo, (void*)out);
}